// Round 2
// baseline (242.049 us; speedup 1.0000x reference)
//
#include <hip/hip_runtime.h>

#define NUM_IDS 8192
#define D 512

// ---------------- kernels ----------------

// Fused histogram + scan. Grid-stride atomic count; the LAST block to finish
// (device-scope ticket) performs the dual exclusive scan over (present, count),
// writing rank/offs/cursor/nuniq and the uniq_ids output.
__global__ __launch_bounds__(256) void k_count_scan(
    const int* __restrict__ labels, int n,
    int* __restrict__ cnt,            // [NUM_IDS + pad]; cnt[NUM_IDS] = done ticket
    int* __restrict__ rank,
    int* __restrict__ offs,
    int* __restrict__ cursor,
    int* __restrict__ nuniq,
    float* __restrict__ uniq_out)
{
    int tid = blockIdx.x * 256 + threadIdx.x;
    int stride = gridDim.x * 256;
    for (int i = tid; i < n; i += stride)
        atomicAdd(&cnt[labels[i]], 1);

    __threadfence();   // make this block's atomics visible before ticket
    __shared__ int s_last;
    if (threadIdx.x == 0) {
        int ticket = __hip_atomic_fetch_add(&cnt[NUM_IDS], 1,
                                            __ATOMIC_ACQ_REL, __HIP_MEMORY_SCOPE_AGENT);
        s_last = (ticket == (int)gridDim.x - 1) ? 1 : 0;
    }
    __syncthreads();
    if (!s_last) return;

    // ---- scan by the last block: 256 threads x 32 ids each ----
    int t = threadIdx.x;
    int lane = t & 63, wave = t >> 6;
    int base = t * 32;

    int fs = 0, cs = 0;
#pragma unroll
    for (int j = 0; j < 32; ++j) {
        int c = __hip_atomic_load(&cnt[base + j], __ATOMIC_RELAXED, __HIP_MEMORY_SCOPE_AGENT);
        fs += (c > 0); cs += c;
    }
    // inclusive wave scan (64 lanes)
    int fi = fs, ci = cs;
#pragma unroll
    for (int d = 1; d < 64; d <<= 1) {
        int fo = __shfl_up(fi, d, 64);
        int co = __shfl_up(ci, d, 64);
        if (lane >= d) { fi += fo; ci += co; }
    }
    __shared__ int s_f[4], s_c[4], s_total;
    if (lane == 63) { s_f[wave] = fi; s_c[wave] = ci; }
    __syncthreads();
    if (t == 0) {
        int af = 0, ac = 0;
#pragma unroll
        for (int w = 0; w < 4; ++w) {
            int tf = s_f[w], tc = s_c[w];
            s_f[w] = af; s_c[w] = ac;   // exclusive wave offsets
            af += tf; ac += tc;
        }
        s_total = af;
        nuniq[0] = af;
    }
    __syncthreads();
    int fexcl = (fi - fs) + s_f[wave];
    int cexcl = (ci - cs) + s_c[wave];
    int total = s_total;
#pragma unroll
    for (int j = 0; j < 32; ++j) {
        int id = base + j;
        int c = __hip_atomic_load(&cnt[id], __ATOMIC_RELAXED, __HIP_MEMORY_SCOPE_AGENT);
        rank[id] = fexcl;
        offs[id] = cexcl;
        cursor[id] = cexcl;                       // fill cursors start at CSR offset
        if (c > 0) uniq_out[fexcl] = (float)id;   // sorted unique ids
        if (id >= total) uniq_out[id] = -1.0f;    // jnp.unique fill_value tail
        fexcl += (c > 0);
        cexcl += c;
    }
}

// CSR fill: one atomic bump per row, direct write (cursor pre-seeded to offs).
__global__ __launch_bounds__(256) void k_fill(const int* __restrict__ labels, int n,
                                              int* __restrict__ cursor,
                                              int* __restrict__ rowidx) {
    int i = blockIdx.x * 256 + threadIdx.x;
    if (i < n) {
        int p = atomicAdd(&cursor[labels[i]], 1);
        rowidx[p] = i;
    }
}

// One block per id; 128 threads, thread t owns float4 column t.
// 4-way unrolled: 4 independent 1KB wave-loads in flight per wave.
__global__ __launch_bounds__(128) void k_agg(const float* __restrict__ emb,
                                             const int* __restrict__ cnt,
                                             const int* __restrict__ rank,
                                             const int* __restrict__ offs,
                                             const int* __restrict__ rowidx,
                                             const int* __restrict__ nuniq,
                                             float* __restrict__ agg) {
    int id = blockIdx.x;
    int t = threadIdx.x;
    int n = cnt[id];
    const float4* eb = reinterpret_cast<const float4*>(emb);

    if (n == 0) {
        // absent id -> tail row; segment_sum leaves it 0, /max(1)=0
        int outrow = nuniq[0] + (id - rank[id]);
        float4 z = {0.f, 0.f, 0.f, 0.f};
        reinterpret_cast<float4*>(agg + (size_t)outrow * D)[t] = z;
        return;
    }
    int off = offs[id];
    float4 a0 = {0,0,0,0}, a1 = {0,0,0,0}, a2 = {0,0,0,0}, a3 = {0,0,0,0};
    int r = 0;
    for (; r + 4 <= n; r += 4) {
        int r0 = rowidx[off + r + 0];
        int r1 = rowidx[off + r + 1];
        int r2 = rowidx[off + r + 2];
        int r3 = rowidx[off + r + 3];
        float4 v0 = eb[(size_t)r0 * (D / 4) + t];
        float4 v1 = eb[(size_t)r1 * (D / 4) + t];
        float4 v2 = eb[(size_t)r2 * (D / 4) + t];
        float4 v3 = eb[(size_t)r3 * (D / 4) + t];
        a0.x += v0.x; a0.y += v0.y; a0.z += v0.z; a0.w += v0.w;
        a1.x += v1.x; a1.y += v1.y; a1.z += v1.z; a1.w += v1.w;
        a2.x += v2.x; a2.y += v2.y; a2.z += v2.z; a2.w += v2.w;
        a3.x += v3.x; a3.y += v3.y; a3.z += v3.z; a3.w += v3.w;
    }
    for (; r < n; ++r) {
        int r0 = rowidx[off + r];
        float4 v0 = eb[(size_t)r0 * (D / 4) + t];
        a0.x += v0.x; a0.y += v0.y; a0.z += v0.z; a0.w += v0.w;
    }
    float inv = 1.0f / (float)n;
    float4 o;
    o.x = ((a0.x + a1.x) + (a2.x + a3.x)) * inv;
    o.y = ((a0.y + a1.y) + (a2.y + a3.y)) * inv;
    o.z = ((a0.z + a1.z) + (a2.z + a3.z)) * inv;
    o.w = ((a0.w + a1.w) + (a2.w + a3.w)) * inv;
    reinterpret_cast<float4*>(agg + (size_t)rank[id] * D)[t] = o;
}

// ---------------- launch ----------------

extern "C" void kernel_launch(void* const* d_in, const int* in_sizes, int n_in,
                              void* d_out, int out_size, void* d_ws, size_t ws_size,
                              hipStream_t stream) {
    const float* emb   = (const float*)d_in[0];
    const int* labels  = (const int*)d_in[1];
    const int n = in_sizes[1];

    float* agg  = (float*)d_out;                       // [NUM_IDS, D]
    float* uniq = agg + (size_t)NUM_IDS * D;           // [NUM_IDS]

    int* ws     = (int*)d_ws;
    int* cnt    = ws;                                  // [NUM_IDS + 64] (+ ticket)
    int* rank   = ws + NUM_IDS + 64;                   // [NUM_IDS]
    int* offs   = rank + NUM_IDS;                      // [NUM_IDS]
    int* cursor = offs + NUM_IDS;                      // [NUM_IDS]
    int* nuniq  = cursor + NUM_IDS;                    // [1] (+pad)
    int* rowidx = nuniq + 64;                          // [n]

    // zero cnt + ticket via graph memset node (replaces k_zero dispatch)
    hipMemsetAsync(cnt, 0, (NUM_IDS + 64) * sizeof(int), stream);

    k_count_scan<<<1024, 256, 0, stream>>>(labels, n, cnt, rank, offs, cursor, nuniq, uniq);
    k_fill      <<<(n + 255) / 256, 256, 0, stream>>>(labels, n, cursor, rowidx);
    k_agg       <<<NUM_IDS, 128, 0, stream>>>(emb, cnt, rank, offs, rowidx, nuniq, agg);
}

// Round 3
// 147.119 us; speedup vs baseline: 1.6453x; 1.6453x over previous
//
#include <hip/hip_runtime.h>

#define NUM_IDS 8192
#define D 512

// ---------------- kernels ----------------

__global__ __launch_bounds__(256) void k_zero(int* __restrict__ cnt) {
    int i = blockIdx.x * 256 + threadIdx.x;
    if (i < NUM_IDS) cnt[i] = 0;
}

// Histogram + per-element arrival order (pos). One atomic per element.
__global__ __launch_bounds__(256) void k_count(const int* __restrict__ labels, int n,
                                               int* __restrict__ cnt,
                                               int* __restrict__ pos) {
    int i = blockIdx.x * 256 + threadIdx.x;
    if (i < n) pos[i] = atomicAdd(&cnt[labels[i]], 1);
}

// One block, 1024 threads, 8 ids/thread. Dual exclusive scan over
// (present flag, count) -> rank[], offs[], num_unique; writes uniq_ids output.
__global__ __launch_bounds__(1024) void k_scan(const int* __restrict__ cnt,
                                               int* __restrict__ rank,
                                               int* __restrict__ offs,
                                               int* __restrict__ nuniq,
                                               float* __restrict__ uniq_out) {
    __shared__ int s_f[16], s_c[16];
    __shared__ int s_total;
    int t = threadIdx.x;
    int lane = t & 63, wave = t >> 6;
    int c[8], f[8];
    int fs = 0, cs = 0;
    int base = t * 8;
#pragma unroll
    for (int j = 0; j < 8; ++j) {
        c[j] = cnt[base + j];
        f[j] = (c[j] > 0) ? 1 : 0;
        fs += f[j]; cs += c[j];
    }
    // inclusive wave scan (wave = 64 lanes on CDNA)
    int fi = fs, ci = cs;
#pragma unroll
    for (int d = 1; d < 64; d <<= 1) {
        int fo = __shfl_up(fi, d, 64);
        int co = __shfl_up(ci, d, 64);
        if (lane >= d) { fi += fo; ci += co; }
    }
    if (lane == 63) { s_f[wave] = fi; s_c[wave] = ci; }
    __syncthreads();
    if (t == 0) {
        int af = 0, ac = 0;
#pragma unroll
        for (int w = 0; w < 16; ++w) {
            int tf = s_f[w], tc = s_c[w];
            s_f[w] = af; s_c[w] = ac;   // exclusive wave offsets
            af += tf; ac += tc;
        }
        s_total = af;
        nuniq[0] = af;
    }
    __syncthreads();
    int fexcl = (fi - fs) + s_f[wave];
    int cexcl = (ci - cs) + s_c[wave];
    int total = s_total;
#pragma unroll
    for (int j = 0; j < 8; ++j) {
        int id = base + j;
        rank[id] = fexcl;
        offs[id] = cexcl;
        if (f[j]) uniq_out[fexcl] = (float)id;   // sorted unique ids
        if (id >= total) uniq_out[id] = -1.0f;   // jnp.unique fill_value tail
        fexcl += f[j];
        cexcl += c[j];
    }
}

// CSR fill, atomic-free: position = offs[label] + arrival order from k_count.
__global__ __launch_bounds__(256) void k_fill(const int* __restrict__ labels, int n,
                                              const int* __restrict__ offs,
                                              const int* __restrict__ pos,
                                              int* __restrict__ rowidx) {
    int i = blockIdx.x * 256 + threadIdx.x;
    if (i < n) {
        rowidx[offs[labels[i]] + pos[i]] = i;
    }
}

// One block per id; 128 threads, thread t owns float4 column t.
// 4-way unrolled: 4 independent 2KB row-loads in flight per block.
__global__ __launch_bounds__(128) void k_agg(const float* __restrict__ emb,
                                             const int* __restrict__ cnt,
                                             const int* __restrict__ rank,
                                             const int* __restrict__ offs,
                                             const int* __restrict__ rowidx,
                                             const int* __restrict__ nuniq,
                                             float* __restrict__ agg) {
    int id = blockIdx.x;
    int t = threadIdx.x;
    int n = cnt[id];
    const float4* eb = reinterpret_cast<const float4*>(emb);

    if (n == 0) {
        // absent id -> tail row; segment_sum leaves it 0, /max(1)=0
        int outrow = nuniq[0] + (id - rank[id]);
        float4 z = {0.f, 0.f, 0.f, 0.f};
        reinterpret_cast<float4*>(agg + (size_t)outrow * D)[t] = z;
        return;
    }
    int off = offs[id];
    float4 a0 = {0,0,0,0}, a1 = {0,0,0,0}, a2 = {0,0,0,0}, a3 = {0,0,0,0};
    int r = 0;
    for (; r + 4 <= n; r += 4) {
        int r0 = rowidx[off + r + 0];
        int r1 = rowidx[off + r + 1];
        int r2 = rowidx[off + r + 2];
        int r3 = rowidx[off + r + 3];
        float4 v0 = eb[(size_t)r0 * (D / 4) + t];
        float4 v1 = eb[(size_t)r1 * (D / 4) + t];
        float4 v2 = eb[(size_t)r2 * (D / 4) + t];
        float4 v3 = eb[(size_t)r3 * (D / 4) + t];
        a0.x += v0.x; a0.y += v0.y; a0.z += v0.z; a0.w += v0.w;
        a1.x += v1.x; a1.y += v1.y; a1.z += v1.z; a1.w += v1.w;
        a2.x += v2.x; a2.y += v2.y; a2.z += v2.z; a2.w += v2.w;
        a3.x += v3.x; a3.y += v3.y; a3.z += v3.z; a3.w += v3.w;
    }
    for (; r < n; ++r) {
        int r0 = rowidx[off + r];
        float4 v0 = eb[(size_t)r0 * (D / 4) + t];
        a0.x += v0.x; a0.y += v0.y; a0.z += v0.z; a0.w += v0.w;
    }
    float inv = 1.0f / (float)n;
    float4 o;
    o.x = ((a0.x + a1.x) + (a2.x + a3.x)) * inv;
    o.y = ((a0.y + a1.y) + (a2.y + a3.y)) * inv;
    o.z = ((a0.z + a1.z) + (a2.z + a3.z)) * inv;
    o.w = ((a0.w + a1.w) + (a2.w + a3.w)) * inv;
    reinterpret_cast<float4*>(agg + (size_t)rank[id] * D)[t] = o;
}

// ---------------- launch ----------------

extern "C" void kernel_launch(void* const* d_in, const int* in_sizes, int n_in,
                              void* d_out, int out_size, void* d_ws, size_t ws_size,
                              hipStream_t stream) {
    const float* emb   = (const float*)d_in[0];
    const int* labels  = (const int*)d_in[1];
    const int n = in_sizes[1];

    float* agg  = (float*)d_out;                       // [NUM_IDS, D]
    float* uniq = agg + (size_t)NUM_IDS * D;           // [NUM_IDS]

    int* ws     = (int*)d_ws;
    int* cnt    = ws;                                  // [NUM_IDS]
    int* rank   = ws + NUM_IDS;                        // [NUM_IDS]
    int* offs   = rank + NUM_IDS;                      // [NUM_IDS]
    int* nuniq  = offs + NUM_IDS;                      // [1] (+pad)
    int* pos    = nuniq + 64;                          // [n]
    int* rowidx = pos + n;                             // [n]

    k_zero <<<NUM_IDS / 256, 256, 0, stream>>>(cnt);
    k_count<<<(n + 255) / 256, 256, 0, stream>>>(labels, n, cnt, pos);
    k_scan <<<1, 1024, 0, stream>>>(cnt, rank, offs, nuniq, uniq);
    k_fill <<<(n + 255) / 256, 256, 0, stream>>>(labels, n, offs, pos, rowidx);
    k_agg  <<<NUM_IDS, 128, 0, stream>>>(emb, cnt, rank, offs, rowidx, nuniq, agg);
}